// Round 4
// baseline (1330.549 us; speedup 1.0000x reference)
//
#include <hip/hip_runtime.h>
#include <hip/hip_bf16.h>
#include <stdint.h>

typedef __bf16 bf16_t;
typedef __bf16 bf16x2 __attribute__((ext_vector_type(2)));
typedef __bf16 bf16x8 __attribute__((ext_vector_type(8)));
typedef float f32x4 __attribute__((ext_vector_type(4)));

#define NB 256
#define NS 256
#define NE 384
#define NH 6
#define ND 64
#define NM (NB*NS)   // 65536 rows

__device__ __forceinline__ f32x4 mfma16(bf16x8 a, bf16x8 b, f32x4 c) {
    return __builtin_amdgcn_mfma_f32_16x16x32_bf16(a, b, c, 0, 0, 0);
}

__device__ __forceinline__ void cp16_async(const bf16_t* g, const bf16_t* l) {
    __builtin_amdgcn_global_load_lds(
        (__attribute__((address_space(1))) void*)g,
        (__attribute__((address_space(3))) void*)l, 16, 0, 0);
}

// ---------------- weight prep ----------------
__global__ void wqkv_trans(const float* __restrict__ Wq, const float* __restrict__ Wk,
                           const float* __restrict__ Wv, bf16_t* __restrict__ Wcat)
{
    int i = blockIdx.x * 256 + threadIdx.x;   // over H*E*DH = 147456
    if (i >= NH*NE*ND) return;
    int d = i & 63;
    int e = (i >> 6) % NE;
    int h = i / (NE*ND);
    int n = h*64 + d;
    Wcat[(size_t)n*NE + e]         = (bf16_t)Wq[i];
    Wcat[(size_t)(384 + n)*NE + e] = (bf16_t)Wk[i];
    Wcat[(size_t)(768 + n)*NE + e] = (bf16_t)Wv[i];
}

__global__ void wtrans(const float* __restrict__ src, bf16_t* __restrict__ dst, int K, int N)
{
    int i = blockIdx.x * 256 + threadIdx.x;   // over K*N
    if (i >= K*N) return;
    int k = i / N, n = i % N;
    dst[(size_t)n*K + k] = (bf16_t)src[i];
}

// ---------------- layernorm: one wave per row of 384 ----------------
__global__ __launch_bounds__(256) void ln_kernel(
    const float* __restrict__ x, const float* __restrict__ g,
    const float* __restrict__ be, bf16_t* __restrict__ o)
{
    const int wave = threadIdx.x >> 6, lane = threadIdx.x & 63;
    const int row = blockIdx.x * 4 + wave;
    const float* xr = x + (size_t)row * NE;
    float v[6]; float s = 0.f, sq = 0.f;
    #pragma unroll
    for (int i = 0; i < 6; i++) { v[i] = xr[i*64 + lane]; s += v[i]; sq += v[i]*v[i]; }
    #pragma unroll
    for (int off = 32; off > 0; off >>= 1) { s += __shfl_xor(s, off); sq += __shfl_xor(sq, off); }
    const float mean = s * (1.f/NE);
    const float rstd = rsqrtf(sq * (1.f/NE) - mean*mean + 1e-5f);
    bf16_t* orow = o + (size_t)row * NE;
    #pragma unroll
    for (int i = 0; i < 6; i++) {
        int e = i*64 + lane;
        orow[e] = (bf16_t)((v[i] - mean) * rstd * g[e] + be[e]);
    }
}

// ---------------- persistent W-in-LDS barrier-free GEMM (K = 384) ----------------
// One block = one 192-col weight chunk staged to LDS ONCE (XOR-swizzled),
// then a barrier-free loop over 128-row M-strips. 8 waves x 16 rows each;
// A lives in registers (12 x bf16x8 per wave, double-buffered across strips).
// B rows are W^T rows (N x K). OUT_MODE: 1 = bf16 scatter to qkv, 2 = fp32
// row-major (+res), 3 = bf16 row-major.
template<int OUT_MODE, bool RELU>
__global__ __launch_bounds__(512, 2) void gemm_persist(
    const bf16_t* __restrict__ A, const bf16_t* __restrict__ Bt,
    void* __restrict__ outp, const float* __restrict__ bias,
    const float* __restrict__ res, int M, int N)
{
    __shared__ bf16_t sW[12*192*32];   // [kc][row][32] with quad XOR swizzle, 147456 B

    const int tid = threadIdx.x;
    const int wv = tid >> 6, lane = tid & 63;
    const int l15 = lane & 15, quad = lane >> 4;
    const int qs = quad ^ (l15 & 3);          // swizzled quad slot for reads
    const int n0 = blockIdx.y * 192;

    // ---- stage W chunk once: 192 rows x 384 cols = 9216 x 16B ----
    #pragma unroll
    for (int i = 0; i < 18; i++) {
        int idx = i*512 + tid;                 // 0..9215
        int row = idx / 48;
        int q48 = idx % 48;
        int kc = q48 >> 2, q = q48 & 3;
        bf16x8 v = *(const bf16x8*)(Bt + (size_t)(n0 + row)*NE + kc*32 + q*8);
        *(bf16x8*)&sW[(kc*192 + row)*32 + (q ^ (row & 3))*8] = v;
    }
    __syncthreads();   // the only barrier in the kernel

    // preload bias for my 12 n-tiles
    float bias_v[12];
    #pragma unroll
    for (int ni = 0; ni < 12; ni++)
        bias_v[ni] = bias ? bias[n0 + ni*16 + l15] : 0.f;

    const bf16_t* Ap = A + (size_t)(wv*16 + l15)*NE + quad*8;
    const int nstrips = M >> 7;

    bf16x8 aA[12], aB[12];

    auto loadA = [&](bf16x8* dst, int s) {
        const bf16_t* p = Ap + (size_t)s*128*NE;
        #pragma unroll
        for (int kc = 0; kc < 12; kc++) dst[kc] = *(const bf16x8*)(p + kc*32);
    };

    auto computeStore = [&](const bf16x8* a, int s) {
        const int rowb = s*128 + wv*16;
        #pragma unroll
        for (int ng = 0; ng < 3; ng++) {
            f32x4 acc[4];
            const f32x4 zero = {0.f, 0.f, 0.f, 0.f};
            #pragma unroll
            for (int j = 0; j < 4; j++) acc[j] = zero;
            #pragma unroll
            for (int kc = 0; kc < 12; kc++) {
                #pragma unroll
                for (int j = 0; j < 4; j++) {
                    const int r = (ng*4 + j)*16 + l15;
                    bf16x8 bfrag = *(const bf16x8*)&sW[(kc*192 + r)*32 + qs*8];
                    acc[j] = mfma16(a[kc], bfrag, acc[j]);
                }
            }
            #pragma unroll
            for (int j = 0; j < 4; j++) {
                const int ni = ng*4 + j;
                const int gn = n0 + ni*16 + l15;
                #pragma unroll
                for (int rr = 0; rr < 4; rr++) {
                    const int gm = rowb + quad*4 + rr;
                    float v = acc[j][rr] + bias_v[ni];
                    if (res) v += res[(size_t)gm*N + gn];
                    if (RELU) v = fmaxf(v, 0.f);
                    if (OUT_MODE == 1) {
                        int sel = (gn >= 768) ? 2 : ((gn >= 384) ? 1 : 0);
                        int within = gn - sel*384;
                        int b = gm >> 8, s2 = gm & 255, h = within >> 6, d = within & 63;
                        ((bf16_t*)outp)[(size_t)sel*((size_t)NM*384) +
                                        (((size_t)b*NH + h)*NS + s2)*ND + d] = (bf16_t)v;
                    } else if (OUT_MODE == 2) {
                        ((float*)outp)[(size_t)gm*N + gn] = v;
                    } else {
                        ((bf16_t*)outp)[(size_t)gm*N + gn] = (bf16_t)v;
                    }
                }
            }
        }
    };

    // strips per block is 2*k (gridDim.x = 128, nstrips in {256, 512})
    const int g = gridDim.x;
    loadA(aA, blockIdx.x);
    for (int s = blockIdx.x; s < nstrips; s += 2*g) {
        loadA(aB, s + g);                       // always valid (nstrips % 256 == 0)
        computeStore(aA, s);
        if (s + 2*g < nstrips) loadA(aA, s + 2*g);
        computeStore(aB, s + g);
    }
}

// ---------------- wide-N bf16 MFMA GEMM (kept for FFN2, K large) ----------------
template<int OUT_MODE, bool RELU>
__global__ __launch_bounds__(512, 2) void gemm_wide(
    const bf16_t* __restrict__ A, const bf16_t* __restrict__ Bt,
    void* __restrict__ outp, const float* __restrict__ bias,
    const float* __restrict__ res, int M, int N, int K, int ldb)
{
    __shared__ bf16_t sAB[3][512*32];   // rows 0..127 = A tile, 128..511 = B panel
    const int tid = threadIdx.x;
    const int wave = tid >> 6, lane = tid & 63;
    const int l15 = lane & 15, quad = lane >> 4;
    const int m0 = blockIdx.x * 128;
    const int n0 = blockIdx.y * 384;
    const int wm = wave >> 2, wn = wave & 3;    // 2 x 4 wave grid

    const int srow = lane >> 2;
    const int scol = (lane & 3) * 8;
    const int r0 = 64 * wave;

    const bf16_t* gsrc;
    size_t rs;
    if (wave < 2) { gsrc = A  + (size_t)(m0 + r0 + srow) * K + scol;         rs = (size_t)K; }
    else          { gsrc = Bt + (size_t)(n0 + r0 - 128 + srow) * ldb + scol; rs = (size_t)ldb; }

    const f32x4 zero = {0.f, 0.f, 0.f, 0.f};
    f32x4 acc[4][6];
    #pragma unroll
    for (int a = 0; a < 4; a++)
        #pragma unroll
        for (int b = 0; b < 6; b++) acc[a][b] = zero;

    const int nk = K >> 5;

    auto issue = [&](int t, int slot) {
        const int kt = t << 5;
        #pragma unroll
        for (int i = 0; i < 4; i++)
            cp16_async(gsrc + (size_t)(16*i)*rs + kt, &sAB[slot][(r0 + 16*i)*32]);
    };

    issue(0, 0);
    issue(1, 1);

    int cb = 0;
    int ns = 2;
    for (int it = 0; it < nk; ++it) {
        asm volatile("s_barrier" ::: "memory");
        if (it + 2 < nk) {
            issue(it + 2, ns);
            asm volatile("s_waitcnt vmcnt(8)\n\ts_barrier" ::: "memory");
        } else if (it + 1 < nk) {
            asm volatile("s_waitcnt vmcnt(4)\n\ts_barrier" ::: "memory");
        } else {
            asm volatile("s_waitcnt vmcnt(0)\n\ts_barrier" ::: "memory");
        }

        bf16x8 bfr[6];
        #pragma unroll
        for (int i = 0; i < 6; i++)
            bfr[i] = *(const bf16x8*)&sAB[cb][(128 + 96*wn + 16*i + l15)*32 + quad*8];
        #pragma unroll
        for (int mi = 0; mi < 4; mi++) {
            bf16x8 af = *(const bf16x8*)&sAB[cb][(64*wm + 16*mi + l15)*32 + quad*8];
            #pragma unroll
            for (int ni = 0; ni < 6; ni++)
                acc[mi][ni] = mfma16(af, bfr[ni], acc[mi][ni]);
        }

        cb = (cb == 2) ? 0 : cb + 1;
        ns = (ns == 2) ? 0 : ns + 1;
    }

    #pragma unroll
    for (int mi = 0; mi < 4; mi++) {
        #pragma unroll
        for (int ni = 0; ni < 6; ni++) {
            #pragma unroll
            for (int r = 0; r < 4; r++) {
                int gm = m0 + 64*wm + 16*mi + quad*4 + r;
                int gn = n0 + 96*wn + 16*ni + l15;
                float v = acc[mi][ni][r];
                if (bias) v += bias[gn];
                if (res)  v += res[(size_t)gm*N + gn];
                if (RELU) v = fmaxf(v, 0.f);
                if (OUT_MODE == 2) {
                    ((float*)outp)[(size_t)gm*N + gn] = v;
                } else {
                    ((bf16_t*)outp)[(size_t)gm*N + gn] = (bf16_t)v;
                }
            }
        }
    }
}

// ---------------- fused causal attention: one block per (b,h) ----------------
__global__ __launch_bounds__(256) void attn_kernel(
    const bf16_t* __restrict__ Qg, const bf16_t* __restrict__ Kg,
    const bf16_t* __restrict__ Vg, bf16_t* __restrict__ Og)
{
    __shared__ bf16_t sK[256*72];    // [t][72] padded
    __shared__ bf16_t sVT[64*264];   // [d][264] padded (V transposed)
    __shared__ bf16_t sQ[64*72];     // current 64-row Q tile
    __shared__ bf16_t sS[64*264];    // scores, then unnormalized P
    __shared__ float sMax[64*4];
    __shared__ float sSum[64*4];
    __shared__ float sRowSum[64];

    const int tid = threadIdx.x;
    const int wave = tid >> 6, lane = tid & 63;
    const int l15 = lane & 15, quad = lane >> 4;
    const int bh = blockIdx.x;
    const int b = bh / NH, h = bh % NH;
    const size_t base = (size_t)bh * (NS*ND);
    const bf16_t* Qb = Qg + base;
    const bf16_t* Kb = Kg + base;
    const bf16_t* Vb = Vg + base;

    #pragma unroll
    for (int it = 0; it < 8; it++) {
        int idx = it*256 + tid;        // 0..2047
        int t = idx >> 3, c = idx & 7;
        bf16x8 kv = *(const bf16x8*)(Kb + t*64 + c*8);
        *(bf16x8*)&sK[t*72 + c*8] = kv;
        bf16x8 vv = *(const bf16x8*)(Vb + t*64 + c*8);
        #pragma unroll
        for (int j = 0; j < 8; j++) sVT[(c*8 + j)*264 + t] = vv[j];
    }

    const int r = lane;
    const int p = wave;
    const f32x4 zero = {0.f, 0.f, 0.f, 0.f};

    for (int mt = 0; mt < 4; mt++) {
        __syncthreads();
        #pragma unroll
        for (int it = 0; it < 2; it++) {
            int idx = it*256 + tid;
            int qr = idx >> 3, c = idx & 7;
            *(bf16x8*)&sQ[qr*72 + c*8] = *(const bf16x8*)(Qb + (64*mt + qr)*64 + c*8);
        }
        __syncthreads();
        if (wave <= mt) {
            const int ct = wave;
            bf16x8 bk[2][4];
            #pragma unroll
            for (int ks = 0; ks < 2; ks++)
                #pragma unroll
                for (int ni = 0; ni < 4; ni++)
                    bk[ks][ni] = *(const bf16x8*)&sK[(64*ct + 16*ni + l15)*72 + ks*32 + quad*8];
            #pragma unroll
            for (int mi = 0; mi < 4; mi++) {
                bf16x8 a0 = *(const bf16x8*)&sQ[(16*mi + l15)*72 + quad*8];
                bf16x8 a1 = *(const bf16x8*)&sQ[(16*mi + l15)*72 + 32 + quad*8];
                f32x4 sc[4];
                #pragma unroll
                for (int ni = 0; ni < 4; ni++) sc[ni] = zero;
                #pragma unroll
                for (int ni = 0; ni < 4; ni++) sc[ni] = mfma16(a0, bk[0][ni], sc[ni]);
                #pragma unroll
                for (int ni = 0; ni < 4; ni++) sc[ni] = mfma16(a1, bk[1][ni], sc[ni]);
                #pragma unroll
                for (int ni = 0; ni < 4; ni++)
                    #pragma unroll
                    for (int rr = 0; rr < 4; rr++)
                        sS[(16*mi + quad*4 + rr)*264 + 64*ct + 16*ni + l15] =
                            (bf16_t)(sc[ni][rr] * 0.125f);
            }
        }
        __syncthreads();
        const int sg = 64*mt + r;
        float mx = -INFINITY;
        if (p <= mt) {
            #pragma unroll
            for (int c = 0; c < 8; c++) {
                bf16x8 v8 = *(const bf16x8*)&sS[r*264 + 64*p + c*8];
                #pragma unroll
                for (int j = 0; j < 8; j++) {
                    int t = 64*p + c*8 + j;
                    float v = (float)v8[j];
                    mx = (t <= sg) ? fmaxf(mx, v) : mx;
                }
            }
        }
        sMax[r*4 + p] = mx;
        __syncthreads();
        const float rmax = fmaxf(fmaxf(sMax[r*4+0], sMax[r*4+1]),
                                 fmaxf(sMax[r*4+2], sMax[r*4+3]));
        float sum = 0.f;
        if (p <= mt) {
            #pragma unroll
            for (int c = 0; c < 8; c++) {
                bf16x8 v8 = *(const bf16x8*)&sS[r*264 + 64*p + c*8];
                bf16x8 e8;
                #pragma unroll
                for (int j = 0; j < 8; j++) {
                    int t = 64*p + c*8 + j;
                    float e = 0.f;
                    if (t <= sg) e = __expf((float)v8[j] - rmax);
                    sum += e;
                    e8[j] = (bf16_t)e;
                }
                *(bf16x8*)&sS[r*264 + 64*p + c*8] = e8;
            }
        }
        sSum[r*4 + p] = sum;
        __syncthreads();
        if (p == 0) sRowSum[r] = sSum[r*4+0] + sSum[r*4+1] + sSum[r*4+2] + sSum[r*4+3];
        __syncthreads();
        f32x4 oacc[4];
        #pragma unroll
        for (int ni = 0; ni < 4; ni++) oacc[ni] = zero;
        for (int kt = 0; kt <= mt; kt++) {
            bf16x8 a = *(const bf16x8*)&sS[(16*p + l15)*264 + 64*kt + quad*8];
            #pragma unroll
            for (int ni = 0; ni < 4; ni++) {
                bf16x8 bv = *(const bf16x8*)&sVT[(16*ni + l15)*264 + 64*kt + quad*8];
                oacc[ni] = mfma16(a, bv, oacc[ni]);
            }
        }
        #pragma unroll
        for (int ni = 0; ni < 4; ni++) {
            #pragma unroll
            for (int rr = 0; rr < 4; rr++) {
                int lrow = 16*p + quad*4 + rr;
                float inv = 1.0f / sRowSum[lrow];
                int srow_g = 64*mt + lrow;
                int d = 16*ni + l15;
                Og[((size_t)(b*NS + srow_g))*NE + h*ND + d] = (bf16_t)(oacc[ni][rr] * inv);
            }
        }
    }
}

// ---------------- host launcher ----------------
extern "C" void kernel_launch(void* const* d_in, const int* in_sizes, int n_in,
                              void* d_out, int out_size, void* d_ws, size_t ws_size,
                              hipStream_t stream)
{
    (void)in_sizes; (void)n_in; (void)out_size; (void)ws_size;
    const float* x   = (const float*)d_in[0];
    const float* Wq  = (const float*)d_in[1];
    const float* Wk  = (const float*)d_in[2];
    const float* Wv  = (const float*)d_in[3];
    const float* Wp  = (const float*)d_in[4];
    const float* bp  = (const float*)d_in[5];
    const float* W1  = (const float*)d_in[6];
    const float* b1  = (const float*)d_in[7];
    const float* W2  = (const float*)d_in[8];
    const float* b2  = (const float*)d_in[9];
    const float* g1  = (const float*)d_in[10];
    const float* be1 = (const float*)d_in[11];
    const float* g2  = (const float*)d_in[12];
    const float* be2 = (const float*)d_in[13];
    float* out = (float*)d_out;

    char* ws = (char*)d_ws;
    const size_t SZ = (size_t)NM * NE * 2;           // 48 MiB per bf16 activation
    bf16_t* h_bf  = (bf16_t*)(ws);                   // dead after QKV GEMM
    bf16_t* q_bf  = (bf16_t*)(ws + SZ);              // qkv contiguous: q,k,v
    bf16_t* k_bf  = (bf16_t*)(ws + 2*SZ);
    bf16_t* v_bf  = (bf16_t*)(ws + 3*SZ);
    bf16_t* o_bf  = (bf16_t*)(ws);                   // overlay h (h dead)
    bf16_t* h2_bf = (bf16_t*)(ws);                   // overlay o (o dead after proj)
    bf16_t* hid   = (bf16_t*)(ws + SZ);              // 96 MiB: half-M x 1536 hidden (over dead q,k)
    char* wb = ws + 4*SZ;
    bf16_t* Wcat = (bf16_t*)(wb);                    // 1152*384*2 = 884736
    bf16_t* Wpt  = (bf16_t*)(wb + 884736);
    bf16_t* W1t  = (bf16_t*)(wb + 884736 + 294912);
    bf16_t* W2t  = (bf16_t*)(wb + 884736 + 294912 + 1179648);

    wqkv_trans<<<(NH*NE*ND + 255)/256, 256, 0, stream>>>(Wq, Wk, Wv, Wcat);
    wtrans<<<(NE*NE + 255)/256, 256, 0, stream>>>(Wp, Wpt, NE, NE);
    wtrans<<<(NE*4*NE + 255)/256, 256, 0, stream>>>(W1, W1t, NE, 4*NE);
    wtrans<<<(NE*4*NE + 255)/256, 256, 0, stream>>>(W2, W2t, 4*NE, NE);

    ln_kernel<<<NM/4, 256, 0, stream>>>(x, g1, be1, h_bf);

    // QKV: persistent, 6 x 192-col chunks
    gemm_persist<1,false><<<dim3(128, 6), 512, 0, stream>>>(
        h_bf, Wcat, q_bf, nullptr, nullptr, NM, 1152);

    attn_kernel<<<NB*NH, 256, 0, stream>>>(q_bf, k_bf, v_bf, o_bf);

    // proj: persistent, 2 chunks, +bias +residual(x), fp32 out
    gemm_persist<2,false><<<dim3(128, 2), 512, 0, stream>>>(
        o_bf, Wpt, out, bp, x, NM, NE);

    // ---- FFN: LN2 full M, then per-M-half {FFN1 persistent, FFN2 wide K=1536} ----
    ln_kernel<<<NM/4, 256, 0, stream>>>(out, g2, be2, h2_bf);

    for (int half = 0; half < 2; half++) {
        const size_t roff = (size_t)half * 32768;
        const bf16_t* h2h = h2_bf + roff * NE;
        float* outh = out + roff * NE;
        // FFN1: hid[32768][1536] = relu(h2h @ W1 + b1), persistent over 8 chunks
        gemm_persist<3,true><<<dim3(128, 8), 512, 0, stream>>>(
            h2h, W1t, hid, b1, nullptr, 32768, 1536);
        // FFN2: outh += hid @ W2 + b2 (full K=1536, single fp32 RMW)
        gemm_wide<2,false><<<dim3(256, 1), 512, 0, stream>>>(
            hid, W2t, outh, b2, outh, 32768, NE, 1536, 1536);
    }
}

// Round 5
// 878.094 us; speedup vs baseline: 1.5153x; 1.5153x over previous
//
#include <hip/hip_runtime.h>
#include <hip/hip_bf16.h>
#include <stdint.h>

typedef __bf16 bf16_t;
typedef __bf16 bf16x2 __attribute__((ext_vector_type(2)));
typedef __bf16 bf16x8 __attribute__((ext_vector_type(8)));
typedef float f32x4 __attribute__((ext_vector_type(4)));

#define NB 256
#define NS 256
#define NE 384
#define NH 6
#define ND 64
#define NM (NB*NS)   // 65536 rows

__device__ __forceinline__ f32x4 mfma16(bf16x8 a, bf16x8 b, f32x4 c) {
    return __builtin_amdgcn_mfma_f32_16x16x32_bf16(a, b, c, 0, 0, 0);
}

__device__ __forceinline__ void cp16_async(const bf16_t* g, const bf16_t* l) {
    __builtin_amdgcn_global_load_lds(
        (__attribute__((address_space(1))) void*)g,
        (__attribute__((address_space(3))) void*)l, 16, 0, 0);
}

// ---------------- weight prep ----------------
__global__ void wqkv_trans(const float* __restrict__ Wq, const float* __restrict__ Wk,
                           const float* __restrict__ Wv, bf16_t* __restrict__ Wcat)
{
    int i = blockIdx.x * 256 + threadIdx.x;   // over H*E*DH = 147456
    if (i >= NH*NE*ND) return;
    int d = i & 63;
    int e = (i >> 6) % NE;
    int h = i / (NE*ND);
    int n = h*64 + d;
    Wcat[(size_t)n*NE + e]         = (bf16_t)Wq[i];
    Wcat[(size_t)(384 + n)*NE + e] = (bf16_t)Wk[i];
    Wcat[(size_t)(768 + n)*NE + e] = (bf16_t)Wv[i];
}

__global__ void wtrans(const float* __restrict__ src, bf16_t* __restrict__ dst, int K, int N)
{
    int i = blockIdx.x * 256 + threadIdx.x;   // over K*N
    if (i >= K*N) return;
    int k = i / N, n = i % N;
    dst[(size_t)n*K + k] = (bf16_t)src[i];
}

// ---------------- layernorm: one wave per row of 384 ----------------
__global__ __launch_bounds__(256) void ln_kernel(
    const float* __restrict__ x, const float* __restrict__ g,
    const float* __restrict__ be, bf16_t* __restrict__ o)
{
    const int wave = threadIdx.x >> 6, lane = threadIdx.x & 63;
    const int row = blockIdx.x * 4 + wave;
    const float* xr = x + (size_t)row * NE;
    float v[6]; float s = 0.f, sq = 0.f;
    #pragma unroll
    for (int i = 0; i < 6; i++) { v[i] = xr[i*64 + lane]; s += v[i]; sq += v[i]*v[i]; }
    #pragma unroll
    for (int off = 32; off > 0; off >>= 1) { s += __shfl_xor(s, off); sq += __shfl_xor(sq, off); }
    const float mean = s * (1.f/NE);
    const float rstd = rsqrtf(sq * (1.f/NE) - mean*mean + 1e-5f);
    bf16_t* orow = o + (size_t)row * NE;
    #pragma unroll
    for (int i = 0; i < 6; i++) {
        int e = i*64 + lane;
        orow[e] = (bf16_t)((v[i] - mean) * rstd * g[e] + be[e]);
    }
}

// ---------------- A-in-registers GEMM, K=384 (QKV / proj / FFN1) ----------------
// Block = 128-row M-strip; 8 waves x 16 rows; A (16x384) in 48 VGPR/wave, fetched ONCE.
// W^T [N][384] streamed through LDS in 64-col chunks (49 KB, triple-buffered),
// XOR-swizzled (store-side: pre-swizzled global source; read-side: swizzled ds_read).
// OUT_MODE: 1 = bf16 scatter to qkv, 2 = fp32 row-major (+res RMW), 3 = bf16 row-major.
template<int OUT_MODE, bool RELU>
__global__ __launch_bounds__(512, 1) void gemm_areg(
    const bf16_t* __restrict__ A, int lda,
    const bf16_t* __restrict__ Bt, int ldb,
    void* __restrict__ outp, const float* __restrict__ bias,
    const float* __restrict__ res, int N)
{
    __shared__ bf16_t sW[3][24576];   // 3 x 49152 B = 147456 B
    const int tid = threadIdx.x;
    const int wv = tid >> 6, lane = tid & 63;
    const int l15 = lane & 15, quad = lane >> 4;
    const int m0 = blockIdx.x * 128;
    const int nc = N >> 6;

    // pre-swizzled global byte offsets for staging (64 rows x 768 B per chunk)
    uint32_t bo[6];
    #pragma unroll
    for (int i = 0; i < 6; i++) {
        int idx = i*512 + tid;            // 0..3071
        int row = idx / 48, sp = idx % 48;
        bo[i] = (uint32_t)(row * (ldb*2)) + (((uint32_t)(sp*16)) ^ ((uint32_t)((row & 7) << 4)));
    }
    const char* Bbase = (const char*)Bt;

    auto issue = [&](int c, int slot) {
        const char* src = Bbase + (size_t)c * ((size_t)64 * ldb * 2);
        bf16_t* dstb = (bf16_t*)((char*)&sW[slot][0] + tid*16);
        #pragma unroll
        for (int i = 0; i < 6; i++)
            cp16_async((const bf16_t*)(src + bo[i]), dstb + i*4096);
    };

    // A rows -> registers (fetched once)
    const int arow = m0 + wv*16 + l15;
    bf16x8 a[12];
    #pragma unroll
    for (int kc = 0; kc < 12; kc++)
        a[kc] = *(const bf16x8*)(A + (size_t)arow*lda + kc*32 + quad*8);

    issue(0, 0);
    issue(1, 1);

    const int swz = (l15 & 7) << 4;
    int cb = 0, ns = 2;
    for (int j = 0; j < nc; ++j) {
        asm volatile("s_barrier" ::: "memory");       // all waves done reading slot ns
        if (j + 2 < nc) issue(j + 2, ns);
        asm volatile("s_waitcnt vmcnt(12)\n\ts_barrier" ::: "memory");  // chunk j landed

        #pragma unroll
        for (int ni = 0; ni < 4; ni++) {
            f32x4 acc = {0.f, 0.f, 0.f, 0.f};
            const int rowoff = (ni*16 + l15) * 768;   // bytes: 384 bf16 per W row
            #pragma unroll
            for (int kc = 0; kc < 12; kc++) {
                const int kb = (kc*64 + quad*16) ^ swz;
                bf16x8 wf = *(const bf16x8*)((const char*)&sW[cb][0] + rowoff + kb);
                acc = mfma16(a[kc], wf, acc);
            }
            const int gn = j*64 + ni*16 + l15;
            const float bv = bias ? bias[gn] : 0.f;
            #pragma unroll
            for (int rr = 0; rr < 4; rr++) {
                const int gm = m0 + wv*16 + quad*4 + rr;
                float v = acc[rr] + bv;
                if (res)  v += res[(size_t)gm*N + gn];
                if (RELU) v = fmaxf(v, 0.f);
                if (OUT_MODE == 1) {
                    int sel = (gn >= 768) ? 2 : ((gn >= 384) ? 1 : 0);
                    int within = gn - sel*384;
                    int b = gm >> 8, s2 = gm & 255, h = within >> 6, d = within & 63;
                    ((bf16_t*)outp)[(size_t)sel*((size_t)NM*384) +
                                    (((size_t)b*NH + h)*NS + s2)*ND + d] = (bf16_t)v;
                } else if (OUT_MODE == 2) {
                    ((float*)outp)[(size_t)gm*N + gn] = v;
                } else {
                    ((bf16_t*)outp)[(size_t)gm*N + gn] = (bf16_t)v;
                }
            }
        }
        cb = (cb == 2) ? 0 : cb + 1;
        ns = (ns == 2) ? 0 : ns + 1;
    }
}

// ---------------- FFN2: acc-in-registers, K=1536 streamed (one fp32 RMW) ----------------
// Block = 128-row M-strip; wave owns 16 rows x all 384 out-cols (acc 24 x f32x4).
// W2^T [384][1536] k-sliced into 64-col chunks (384 rows x 128 B = 48 KB, tri-buffered);
// hid k-slices prefetched to registers one chunk ahead.
__global__ __launch_bounds__(512, 1) void gemm_ffn2(
    const bf16_t* __restrict__ hid,   // [Mh][1536]
    const bf16_t* __restrict__ W2t,   // [384][1536]
    float* __restrict__ outp,         // [Mh][384], RMW
    const float* __restrict__ b2)
{
    __shared__ bf16_t sW[3][24576];
    const int tid = threadIdx.x;
    const int wv = tid >> 6, lane = tid & 63;
    const int l15 = lane & 15, quad = lane >> 4;
    const int m0 = blockIdx.x * 128;

    uint32_t bo[6];
    #pragma unroll
    for (int i = 0; i < 6; i++) {
        int idx = i*512 + tid;            // 0..3071 over 384 rows x 8 slots
        int row = idx >> 3, sp = idx & 7;
        bo[i] = (uint32_t)(row * 3072) + (((uint32_t)(sp*16)) ^ ((uint32_t)((row & 7) << 4)));
    }

    auto issue = [&](int c, int slot) {
        const char* src = (const char*)W2t + c*128;   // 64-col k-slice
        bf16_t* dstb = (bf16_t*)((char*)&sW[slot][0] + tid*16);
        #pragma unroll
        for (int i = 0; i < 6; i++)
            cp16_async((const bf16_t*)(src + bo[i]), dstb + i*4096);
    };

    const bf16_t* Ap = hid + (size_t)(m0 + wv*16 + l15)*1536 + quad*8;

    f32x4 acc[24];
    #pragma unroll
    for (int i = 0; i < 24; i++) acc[i] = (f32x4){0.f, 0.f, 0.f, 0.f};

    issue(0, 0);
    issue(1, 1);

    bf16x8 aC0 = *(const bf16x8*)(Ap);
    bf16x8 aC1 = *(const bf16x8*)(Ap + 32);
    bf16x8 aN0, aN1;

    const int swz = (l15 & 7) << 4;
    int cb = 0, ns = 2;
    for (int j = 0; j < 24; ++j) {
        asm volatile("s_barrier" ::: "memory");
        if (j + 2 < 24) issue(j + 2, ns);
        asm volatile("s_waitcnt vmcnt(12)\n\ts_barrier" ::: "memory");
        if (j + 1 < 24) {
            aN0 = *(const bf16x8*)(Ap + (j+1)*64);
            aN1 = *(const bf16x8*)(Ap + (j+1)*64 + 32);
        }
        #pragma unroll
        for (int ni = 0; ni < 24; ni++) {
            const int rowoff = (ni*16 + l15) * 128;   // bytes: 64 bf16 per W row-slice
            bf16x8 w0 = *(const bf16x8*)((const char*)&sW[cb][0] + rowoff + ((quad*16) ^ swz));
            bf16x8 w1 = *(const bf16x8*)((const char*)&sW[cb][0] + rowoff + ((64 + quad*16) ^ swz));
            acc[ni] = mfma16(aC0, w0, acc[ni]);
            acc[ni] = mfma16(aC1, w1, acc[ni]);
        }
        aC0 = aN0; aC1 = aN1;
        cb = (cb == 2) ? 0 : cb + 1;
        ns = (ns == 2) ? 0 : ns + 1;
    }

    #pragma unroll
    for (int ni = 0; ni < 24; ni++) {
        const int gn = ni*16 + l15;
        const float bv = b2[gn];
        #pragma unroll
        for (int rr = 0; rr < 4; rr++) {
            const int gm = m0 + wv*16 + quad*4 + rr;
            float* p = outp + (size_t)gm*384 + gn;
            *p = *p + acc[ni][rr] + bv;
        }
    }
}

// ---------------- fused causal attention: one block per (b,h) ----------------
__global__ __launch_bounds__(256) void attn_kernel(
    const bf16_t* __restrict__ Qg, const bf16_t* __restrict__ Kg,
    const bf16_t* __restrict__ Vg, bf16_t* __restrict__ Og)
{
    __shared__ bf16_t sK[256*72];    // [t][72] padded
    __shared__ bf16_t sVT[64*264];   // [d][264] padded (V transposed)
    __shared__ bf16_t sQ[64*72];     // current 64-row Q tile
    __shared__ bf16_t sS[64*264];    // scores, then unnormalized P
    __shared__ float sMax[64*4];
    __shared__ float sSum[64*4];
    __shared__ float sRowSum[64];

    const int tid = threadIdx.x;
    const int wave = tid >> 6, lane = tid & 63;
    const int l15 = lane & 15, quad = lane >> 4;
    const int bh = blockIdx.x;
    const int b = bh / NH, h = bh % NH;
    const size_t base = (size_t)bh * (NS*ND);
    const bf16_t* Qb = Qg + base;
    const bf16_t* Kb = Kg + base;
    const bf16_t* Vb = Vg + base;

    #pragma unroll
    for (int it = 0; it < 8; it++) {
        int idx = it*256 + tid;        // 0..2047
        int t = idx >> 3, c = idx & 7;
        bf16x8 kv = *(const bf16x8*)(Kb + t*64 + c*8);
        *(bf16x8*)&sK[t*72 + c*8] = kv;
        bf16x8 vv = *(const bf16x8*)(Vb + t*64 + c*8);
        #pragma unroll
        for (int j = 0; j < 8; j++) sVT[(c*8 + j)*264 + t] = vv[j];
    }

    const int r = lane;
    const int p = wave;
    const f32x4 zero = {0.f, 0.f, 0.f, 0.f};

    for (int mt = 0; mt < 4; mt++) {
        __syncthreads();
        #pragma unroll
        for (int it = 0; it < 2; it++) {
            int idx = it*256 + tid;
            int qr = idx >> 3, c = idx & 7;
            *(bf16x8*)&sQ[qr*72 + c*8] = *(const bf16x8*)(Qb + (64*mt + qr)*64 + c*8);
        }
        __syncthreads();
        if (wave <= mt) {
            const int ct = wave;
            bf16x8 bk[2][4];
            #pragma unroll
            for (int ks = 0; ks < 2; ks++)
                #pragma unroll
                for (int ni = 0; ni < 4; ni++)
                    bk[ks][ni] = *(const bf16x8*)&sK[(64*ct + 16*ni + l15)*72 + ks*32 + quad*8];
            #pragma unroll
            for (int mi = 0; mi < 4; mi++) {
                bf16x8 a0 = *(const bf16x8*)&sQ[(16*mi + l15)*72 + quad*8];
                bf16x8 a1 = *(const bf16x8*)&sQ[(16*mi + l15)*72 + 32 + quad*8];
                f32x4 sc[4];
                #pragma unroll
                for (int ni = 0; ni < 4; ni++) sc[ni] = zero;
                #pragma unroll
                for (int ni = 0; ni < 4; ni++) sc[ni] = mfma16(a0, bk[0][ni], sc[ni]);
                #pragma unroll
                for (int ni = 0; ni < 4; ni++) sc[ni] = mfma16(a1, bk[1][ni], sc[ni]);
                #pragma unroll
                for (int ni = 0; ni < 4; ni++)
                    #pragma unroll
                    for (int rr = 0; rr < 4; rr++)
                        sS[(16*mi + quad*4 + rr)*264 + 64*ct + 16*ni + l15] =
                            (bf16_t)(sc[ni][rr] * 0.125f);
            }
        }
        __syncthreads();
        const int sg = 64*mt + r;
        float mx = -INFINITY;
        if (p <= mt) {
            #pragma unroll
            for (int c = 0; c < 8; c++) {
                bf16x8 v8 = *(const bf16x8*)&sS[r*264 + 64*p + c*8];
                #pragma unroll
                for (int j = 0; j < 8; j++) {
                    int t = 64*p + c*8 + j;
                    float v = (float)v8[j];
                    mx = (t <= sg) ? fmaxf(mx, v) : mx;
                }
            }
        }
        sMax[r*4 + p] = mx;
        __syncthreads();
        const float rmax = fmaxf(fmaxf(sMax[r*4+0], sMax[r*4+1]),
                                 fmaxf(sMax[r*4+2], sMax[r*4+3]));
        float sum = 0.f;
        if (p <= mt) {
            #pragma unroll
            for (int c = 0; c < 8; c++) {
                bf16x8 v8 = *(const bf16x8*)&sS[r*264 + 64*p + c*8];
                bf16x8 e8;
                #pragma unroll
                for (int j = 0; j < 8; j++) {
                    int t = 64*p + c*8 + j;
                    float e = 0.f;
                    if (t <= sg) e = __expf((float)v8[j] - rmax);
                    sum += e;
                    e8[j] = (bf16_t)e;
                }
                *(bf16x8*)&sS[r*264 + 64*p + c*8] = e8;
            }
        }
        sSum[r*4 + p] = sum;
        __syncthreads();
        if (p == 0) sRowSum[r] = sSum[r*4+0] + sSum[r*4+1] + sSum[r*4+2] + sSum[r*4+3];
        __syncthreads();
        f32x4 oacc[4];
        #pragma unroll
        for (int ni = 0; ni < 4; ni++) oacc[ni] = zero;
        for (int kt = 0; kt <= mt; kt++) {
            bf16x8 a = *(const bf16x8*)&sS[(16*p + l15)*264 + 64*kt + quad*8];
            #pragma unroll
            for (int ni = 0; ni < 4; ni++) {
                bf16x8 bv = *(const bf16x8*)&sVT[(16*ni + l15)*264 + 64*kt + quad*8];
                oacc[ni] = mfma16(a, bv, oacc[ni]);
            }
        }
        #pragma unroll
        for (int ni = 0; ni < 4; ni++) {
            #pragma unroll
            for (int rr = 0; rr < 4; rr++) {
                int lrow = 16*p + quad*4 + rr;
                float inv = 1.0f / sRowSum[lrow];
                int srow_g = 64*mt + lrow;
                int d = 16*ni + l15;
                Og[((size_t)(b*NS + srow_g))*NE + h*ND + d] = (bf16_t)(oacc[ni][rr] * inv);
            }
        }
    }
}

// ---------------- host launcher ----------------
extern "C" void kernel_launch(void* const* d_in, const int* in_sizes, int n_in,
                              void* d_out, int out_size, void* d_ws, size_t ws_size,
                              hipStream_t stream)
{
    (void)in_sizes; (void)n_in; (void)out_size; (void)ws_size;
    const float* x   = (const float*)d_in[0];
    const float* Wq  = (const float*)d_in[1];
    const float* Wk  = (const float*)d_in[2];
    const float* Wv  = (const float*)d_in[3];
    const float* Wp  = (const float*)d_in[4];
    const float* bp  = (const float*)d_in[5];
    const float* W1  = (const float*)d_in[6];
    const float* b1  = (const float*)d_in[7];
    const float* W2  = (const float*)d_in[8];
    const float* b2  = (const float*)d_in[9];
    const float* g1  = (const float*)d_in[10];
    const float* be1 = (const float*)d_in[11];
    const float* g2  = (const float*)d_in[12];
    const float* be2 = (const float*)d_in[13];
    float* out = (float*)d_out;

    char* ws = (char*)d_ws;
    const size_t SZ = (size_t)NM * NE * 2;           // 48 MiB per bf16 activation
    bf16_t* h_bf  = (bf16_t*)(ws);                   // dead after QKV GEMM
    bf16_t* q_bf  = (bf16_t*)(ws + SZ);              // qkv contiguous: q,k,v
    bf16_t* k_bf  = (bf16_t*)(ws + 2*SZ);
    bf16_t* v_bf  = (bf16_t*)(ws + 3*SZ);
    bf16_t* o_bf  = (bf16_t*)(ws);                   // overlay h (h dead)
    bf16_t* h2_bf = (bf16_t*)(ws);                   // overlay o (o dead after proj)
    bf16_t* hid   = (bf16_t*)(ws + SZ);              // 96 MiB: [32768][1536] over dead q,k
    char* wb = ws + 4*SZ;
    bf16_t* Wcat = (bf16_t*)(wb);                    // [1152][384]
    bf16_t* Wpt  = (bf16_t*)(wb + 884736);           // [384][384]
    bf16_t* W1t  = (bf16_t*)(wb + 884736 + 294912);  // [1536][384]
    bf16_t* W2t  = (bf16_t*)(wb + 884736 + 294912 + 1179648);  // [384][1536]

    wqkv_trans<<<(NH*NE*ND + 255)/256, 256, 0, stream>>>(Wq, Wk, Wv, Wcat);
    wtrans<<<(NE*NE + 255)/256, 256, 0, stream>>>(Wp, Wpt, NE, NE);
    wtrans<<<(NE*4*NE + 255)/256, 256, 0, stream>>>(W1, W1t, NE, 4*NE);
    wtrans<<<(NE*4*NE + 255)/256, 256, 0, stream>>>(W2, W2t, 4*NE, NE);

    ln_kernel<<<NM/4, 256, 0, stream>>>(x, g1, be1, h_bf);

    // QKV: A once in regs, Wcat streamed (18 chunks)
    gemm_areg<1,false><<<NM/128, 512, 0, stream>>>(
        h_bf, NE, Wcat, NE, q_bf, nullptr, nullptr, 1152);

    attn_kernel<<<NB*NH, 256, 0, stream>>>(q_bf, k_bf, v_bf, o_bf);

    // proj: +bias +residual(x), fp32 out (6 chunks)
    gemm_areg<2,false><<<NM/128, 512, 0, stream>>>(
        o_bf, NE, Wpt, NE, out, bp, x, NE);

    ln_kernel<<<NM/4, 256, 0, stream>>>(out, g2, be2, h2_bf);

    // ---- FFN per M-half (hid buffer = 96 MiB) ----
    for (int half = 0; half < 2; half++) {
        const size_t roff = (size_t)half * 32768;
        const bf16_t* h2h = h2_bf + roff * NE;
        float* outh = out + roff * NE;
        // FFN1: hid = relu(h2h @ W1 + b1)  (24 chunks)
        gemm_areg<3,true><<<32768/128, 512, 0, stream>>>(
            h2h, NE, W1t, NE, hid, b1, nullptr, 1536);
        // FFN2: outh += hid @ W2 + b2  (K=1536 streamed, single RMW)
        gemm_ffn2<<<32768/128, 512, 0, stream>>>(hid, W2t, outh, b2);
    }
}

// Round 6
// 860.494 us; speedup vs baseline: 1.5463x; 1.0205x over previous
//
#include <hip/hip_runtime.h>
#include <hip/hip_bf16.h>
#include <stdint.h>

typedef __bf16 bf16_t;
typedef __bf16 bf16x2 __attribute__((ext_vector_type(2)));
typedef __bf16 bf16x8 __attribute__((ext_vector_type(8)));
typedef float f32x4 __attribute__((ext_vector_type(4)));

#define NB 256
#define NS 256
#define NE 384
#define NH 6
#define ND 64
#define NM (NB*NS)   // 65536 rows

__device__ __forceinline__ f32x4 mfma16(bf16x8 a, bf16x8 b, f32x4 c) {
    return __builtin_amdgcn_mfma_f32_16x16x32_bf16(a, b, c, 0, 0, 0);
}

__device__ __forceinline__ void cp16_async(const bf16_t* g, const bf16_t* l) {
    __builtin_amdgcn_global_load_lds(
        (__attribute__((address_space(1))) void*)g,
        (__attribute__((address_space(3))) void*)l, 16, 0, 0);
}

// ---------------- weight prep ----------------
__global__ void wqkv_trans(const float* __restrict__ Wq, const float* __restrict__ Wk,
                           const float* __restrict__ Wv, bf16_t* __restrict__ Wcat)
{
    int i = blockIdx.x * 256 + threadIdx.x;   // over H*E*DH = 147456
    if (i >= NH*NE*ND) return;
    int d = i & 63;
    int e = (i >> 6) % NE;
    int h = i / (NE*ND);
    int n = h*64 + d;
    Wcat[(size_t)n*NE + e]         = (bf16_t)Wq[i];
    Wcat[(size_t)(384 + n)*NE + e] = (bf16_t)Wk[i];
    Wcat[(size_t)(768 + n)*NE + e] = (bf16_t)Wv[i];
}

__global__ void wtrans(const float* __restrict__ src, bf16_t* __restrict__ dst, int K, int N)
{
    int i = blockIdx.x * 256 + threadIdx.x;   // over K*N
    if (i >= K*N) return;
    int k = i / N, n = i % N;
    dst[(size_t)n*K + k] = (bf16_t)src[i];
}

// ---------------- layernorm: one wave per row of 384 ----------------
__global__ __launch_bounds__(256) void ln_kernel(
    const float* __restrict__ x, const float* __restrict__ g,
    const float* __restrict__ be, bf16_t* __restrict__ o)
{
    const int wave = threadIdx.x >> 6, lane = threadIdx.x & 63;
    const int row = blockIdx.x * 4 + wave;
    const float* xr = x + (size_t)row * NE;
    float v[6]; float s = 0.f, sq = 0.f;
    #pragma unroll
    for (int i = 0; i < 6; i++) { v[i] = xr[i*64 + lane]; s += v[i]; sq += v[i]*v[i]; }
    #pragma unroll
    for (int off = 32; off > 0; off >>= 1) { s += __shfl_xor(s, off); sq += __shfl_xor(sq, off); }
    const float mean = s * (1.f/NE);
    const float rstd = rsqrtf(sq * (1.f/NE) - mean*mean + 1e-5f);
    bf16_t* orow = o + (size_t)row * NE;
    #pragma unroll
    for (int i = 0; i < 6; i++) {
        int e = i*64 + lane;
        orow[e] = (bf16_t)((v[i] - mean) * rstd * g[e] + be[e]);
    }
}

// ---------------- A-in-registers GEMM, K=384 (QKV / proj / FFN1) ----------------
// Block = 128-row M-strip; 8 waves x 16 rows; A (16x384) in 48 VGPR/wave, fetched ONCE.
// W^T [N][384] streamed through LDS in 64-col chunks (49 KB, triple-buffered),
// XOR-swizzled (store-side: pre-swizzled global source; read-side: swizzled ds_read).
// OUT_MODE: 1 = bf16 scatter to qkv, 2 = fp32 row-major (+res RMW), 3 = bf16 row-major.
template<int OUT_MODE, bool RELU>
__global__ __launch_bounds__(512, 1) void gemm_areg(
    const bf16_t* __restrict__ A, int lda,
    const bf16_t* __restrict__ Bt, int ldb,
    void* __restrict__ outp, const float* __restrict__ bias,
    const float* __restrict__ res, int N)
{
    __shared__ bf16_t sW[3][24576];   // 3 x 49152 B = 147456 B
    const int tid = threadIdx.x;
    const int wv = tid >> 6, lane = tid & 63;
    const int l15 = lane & 15, quad = lane >> 4;
    const int m0 = blockIdx.x * 128;
    const int nc = N >> 6;

    // pre-swizzled global byte offsets for staging (64 rows x 768 B per chunk)
    uint32_t bo[6];
    #pragma unroll
    for (int i = 0; i < 6; i++) {
        int idx = i*512 + tid;            // 0..3071
        int row = idx / 48, sp = idx % 48;
        bo[i] = (uint32_t)(row * (ldb*2)) + (((uint32_t)(sp*16)) ^ ((uint32_t)((row & 7) << 4)));
    }
    const char* Bbase = (const char*)Bt;

    auto issue = [&](int c, int slot) {
        const char* src = Bbase + (size_t)c * ((size_t)64 * ldb * 2);
        bf16_t* dstb = (bf16_t*)((char*)&sW[slot][0] + tid*16);
        #pragma unroll
        for (int i = 0; i < 6; i++)
            cp16_async((const bf16_t*)(src + bo[i]), dstb + i*4096);
    };

    // A rows -> registers (fetched once)
    const int arow = m0 + wv*16 + l15;
    bf16x8 a[12];
    #pragma unroll
    for (int kc = 0; kc < 12; kc++)
        a[kc] = *(const bf16x8*)(A + (size_t)arow*lda + kc*32 + quad*8);

    issue(0, 0);
    issue(1, 1);

    const int swz = (l15 & 7) << 4;
    int cb = 0, ns = 2;
    for (int j = 0; j < nc; ++j) {
        asm volatile("s_barrier" ::: "memory");       // all waves done reading slot ns
        if (j + 2 < nc) issue(j + 2, ns);
        asm volatile("s_waitcnt vmcnt(12)\n\ts_barrier" ::: "memory");  // chunk j landed

        #pragma unroll
        for (int ni = 0; ni < 4; ni++) {
            f32x4 acc = {0.f, 0.f, 0.f, 0.f};
            const int rowoff = (ni*16 + l15) * 768;   // bytes: 384 bf16 per W row
            #pragma unroll
            for (int kc = 0; kc < 12; kc++) {
                const int kb = (kc*64 + quad*16) ^ swz;
                bf16x8 wf = *(const bf16x8*)((const char*)&sW[cb][0] + rowoff + kb);
                acc = mfma16(a[kc], wf, acc);
            }
            const int gn = j*64 + ni*16 + l15;
            const float bv = bias ? bias[gn] : 0.f;
            #pragma unroll
            for (int rr = 0; rr < 4; rr++) {
                const int gm = m0 + wv*16 + quad*4 + rr;
                float v = acc[rr] + bv;
                if (res)  v += res[(size_t)gm*N + gn];
                if (RELU) v = fmaxf(v, 0.f);
                if (OUT_MODE == 1) {
                    int sel = (gn >= 768) ? 2 : ((gn >= 384) ? 1 : 0);
                    int within = gn - sel*384;
                    int b = gm >> 8, s2 = gm & 255, h = within >> 6, d = within & 63;
                    ((bf16_t*)outp)[(size_t)sel*((size_t)NM*384) +
                                    (((size_t)b*NH + h)*NS + s2)*ND + d] = (bf16_t)v;
                } else if (OUT_MODE == 2) {
                    ((float*)outp)[(size_t)gm*N + gn] = v;
                } else {
                    ((bf16_t*)outp)[(size_t)gm*N + gn] = (bf16_t)v;
                }
            }
        }
        cb = (cb == 2) ? 0 : cb + 1;
        ns = (ns == 2) ? 0 : ns + 1;
    }
}

// ---------------- FFN2: acc-in-registers, K=1536 streamed (one fp32 RMW) ----------------
__global__ __launch_bounds__(512, 1) void gemm_ffn2(
    const bf16_t* __restrict__ hid,   // [Mh][1536]
    const bf16_t* __restrict__ W2t,   // [384][1536]
    float* __restrict__ outp,         // [Mh][384], RMW
    const float* __restrict__ b2)
{
    __shared__ bf16_t sW[3][24576];
    const int tid = threadIdx.x;
    const int wv = tid >> 6, lane = tid & 63;
    const int l15 = lane & 15, quad = lane >> 4;
    const int m0 = blockIdx.x * 128;

    uint32_t bo[6];
    #pragma unroll
    for (int i = 0; i < 6; i++) {
        int idx = i*512 + tid;            // 0..3071 over 384 rows x 8 slots
        int row = idx >> 3, sp = idx & 7;
        bo[i] = (uint32_t)(row * 3072) + (((uint32_t)(sp*16)) ^ ((uint32_t)((row & 7) << 4)));
    }

    auto issue = [&](int c, int slot) {
        const char* src = (const char*)W2t + c*128;   // 64-col k-slice
        bf16_t* dstb = (bf16_t*)((char*)&sW[slot][0] + tid*16);
        #pragma unroll
        for (int i = 0; i < 6; i++)
            cp16_async((const bf16_t*)(src + bo[i]), dstb + i*4096);
    };

    const bf16_t* Ap = hid + (size_t)(m0 + wv*16 + l15)*1536 + quad*8;

    f32x4 acc[24];
    #pragma unroll
    for (int i = 0; i < 24; i++) acc[i] = (f32x4){0.f, 0.f, 0.f, 0.f};

    issue(0, 0);
    issue(1, 1);

    bf16x8 aC0 = *(const bf16x8*)(Ap);
    bf16x8 aC1 = *(const bf16x8*)(Ap + 32);
    bf16x8 aN0, aN1;

    const int swz = (l15 & 7) << 4;
    int cb = 0, ns = 2;
    for (int j = 0; j < 24; ++j) {
        asm volatile("s_barrier" ::: "memory");
        if (j + 2 < 24) issue(j + 2, ns);
        asm volatile("s_waitcnt vmcnt(12)\n\ts_barrier" ::: "memory");
        if (j + 1 < 24) {
            aN0 = *(const bf16x8*)(Ap + (j+1)*64);
            aN1 = *(const bf16x8*)(Ap + (j+1)*64 + 32);
        }
        #pragma unroll
        for (int ni = 0; ni < 24; ni++) {
            const int rowoff = (ni*16 + l15) * 128;   // bytes: 64 bf16 per W row-slice
            bf16x8 w0 = *(const bf16x8*)((const char*)&sW[cb][0] + rowoff + ((quad*16) ^ swz));
            bf16x8 w1 = *(const bf16x8*)((const char*)&sW[cb][0] + rowoff + ((64 + quad*16) ^ swz));
            acc[ni] = mfma16(aC0, w0, acc[ni]);
            acc[ni] = mfma16(aC1, w1, acc[ni]);
        }
        aC0 = aN0; aC1 = aN1;
        cb = (cb == 2) ? 0 : cb + 1;
        ns = (ns == 2) ? 0 : ns + 1;
    }

    #pragma unroll
    for (int ni = 0; ni < 24; ni++) {
        const int gn = ni*16 + l15;
        const float bv = b2[gn];
        #pragma unroll
        for (int rr = 0; rr < 4; rr++) {
            const int gm = m0 + wv*16 + quad*4 + rr;
            float* p = outp + (size_t)gm*384 + gn;
            *p = *p + acc[ni][rr] + bv;
        }
    }
}

// ---------------- fused causal attention v2: one block per (b,h), 2 blocks/CU ----------------
// Q/K fragments read directly from global (L1/L2-resident; 16-B contiguous per lane).
// LDS: only V^T + scores (~70 KB). QK^T balanced: wave w computes row-strip w of
// every col-tile. Softmax row-segment register-cached (single LDS read).
__global__ __launch_bounds__(256, 2) void attn_kernel(
    const bf16_t* __restrict__ Qg, const bf16_t* __restrict__ Kg,
    const bf16_t* __restrict__ Vg, bf16_t* __restrict__ Og)
{
    __shared__ bf16_t sVT[64*264];   // [d][264] padded (V transposed)
    __shared__ bf16_t sS[64*264];    // scores, then unnormalized P
    __shared__ float sMax[64*4];
    __shared__ float sSum[64*4];
    __shared__ float sRowSum[64];

    const int tid = threadIdx.x;
    const int wave = tid >> 6, lane = tid & 63;
    const int l15 = lane & 15, quad = lane >> 4;
    const int bh = blockIdx.x;
    const int b = bh / NH, h = bh % NH;
    const size_t base = (size_t)bh * (NS*ND);
    const bf16_t* Qb = Qg + base;
    const bf16_t* Kb = Kg + base;
    const bf16_t* Vb = Vg + base;

    // stage V^T once
    #pragma unroll
    for (int it = 0; it < 8; it++) {
        int idx = it*256 + tid;        // 0..2047
        int t = idx >> 3, c = idx & 7;
        bf16x8 vv = *(const bf16x8*)(Vb + t*64 + c*8);
        #pragma unroll
        for (int j = 0; j < 8; j++) sVT[(c*8 + j)*264 + t] = vv[j];
    }

    const int r = lane;
    const int p = wave;
    const f32x4 zero = {0.f, 0.f, 0.f, 0.f};

    for (int mt = 0; mt < 4; mt++) {
        __syncthreads();   // sVT staged (mt=0) / prev PV done reading sS

        // ---- QK^T: wave handles 16-row strip `wave` of every col-tile ct<=mt ----
        {
            const int qrow = 64*mt + 16*wave + l15;
            bf16x8 a0 = *(const bf16x8*)(Qb + (size_t)qrow*64 + quad*8);
            bf16x8 a1 = *(const bf16x8*)(Qb + (size_t)qrow*64 + 32 + quad*8);
            for (int ct = 0; ct <= mt; ct++) {
                f32x4 sc[4];
                #pragma unroll
                for (int ni = 0; ni < 4; ni++) sc[ni] = zero;
                __builtin_amdgcn_s_setprio(1);
                #pragma unroll
                for (int ni = 0; ni < 4; ni++) {
                    const bf16_t* kr = Kb + (size_t)(64*ct + 16*ni + l15)*64;
                    bf16x8 b0 = *(const bf16x8*)(kr + quad*8);
                    bf16x8 b1 = *(const bf16x8*)(kr + 32 + quad*8);
                    sc[ni] = mfma16(a0, b0, sc[ni]);
                    sc[ni] = mfma16(a1, b1, sc[ni]);
                }
                __builtin_amdgcn_s_setprio(0);
                #pragma unroll
                for (int ni = 0; ni < 4; ni++)
                    #pragma unroll
                    for (int rr = 0; rr < 4; rr++)
                        sS[(16*wave + quad*4 + rr)*264 + 64*ct + 16*ni + l15] =
                            (bf16_t)(sc[ni][rr] * 0.125f);
            }
        }
        __syncthreads();

        // ---- softmax: wave p owns 64-col segment p of row r=lane ----
        const int sg = 64*mt + r;
        const bool active = (p <= mt);
        const bool full = (p < mt);      // whole segment below diagonal
        float mx = -INFINITY;
        bf16x8 v8r[8];
        if (active) {
            #pragma unroll
            for (int c = 0; c < 8; c++)
                v8r[c] = *(const bf16x8*)&sS[r*264 + 64*p + c*8];
            #pragma unroll
            for (int c = 0; c < 8; c++) {
                #pragma unroll
                for (int j = 0; j < 8; j++) {
                    int t = 64*p + c*8 + j;
                    float v = (float)v8r[c][j];
                    mx = (full || t <= sg) ? fmaxf(mx, v) : mx;
                }
            }
        }
        sMax[r*4 + p] = mx;
        __syncthreads();
        const float rmax = fmaxf(fmaxf(sMax[r*4+0], sMax[r*4+1]),
                                 fmaxf(sMax[r*4+2], sMax[r*4+3]));
        float sum = 0.f;
        if (active) {
            #pragma unroll
            for (int c = 0; c < 8; c++) {
                bf16x8 e8;
                #pragma unroll
                for (int j = 0; j < 8; j++) {
                    int t = 64*p + c*8 + j;
                    float e = 0.f;
                    if (full || t <= sg) e = __expf((float)v8r[c][j] - rmax);
                    sum += e;
                    e8[j] = (bf16_t)e;
                }
                *(bf16x8*)&sS[r*264 + 64*p + c*8] = e8;
            }
        }
        sSum[r*4 + p] = sum;
        __syncthreads();
        if (p == 0) sRowSum[r] = sSum[r*4+0] + sSum[r*4+1] + sSum[r*4+2] + sSum[r*4+3];
        __syncthreads();

        // ---- PV: wave p owns output rows 16p..16p+15 ----
        f32x4 oacc[4];
        #pragma unroll
        for (int ni = 0; ni < 4; ni++) oacc[ni] = zero;
        for (int kt = 0; kt <= mt; kt++) {
            bf16x8 a = *(const bf16x8*)&sS[(16*p + l15)*264 + 64*kt + quad*8];
            __builtin_amdgcn_s_setprio(1);
            #pragma unroll
            for (int ni = 0; ni < 4; ni++) {
                bf16x8 bv = *(const bf16x8*)&sVT[(16*ni + l15)*264 + 64*kt + quad*8];
                oacc[ni] = mfma16(a, bv, oacc[ni]);
            }
            __builtin_amdgcn_s_setprio(0);
        }
        #pragma unroll
        for (int ni = 0; ni < 4; ni++) {
            #pragma unroll
            for (int rr = 0; rr < 4; rr++) {
                int lrow = 16*p + quad*4 + rr;
                float inv = 1.0f / sRowSum[lrow];
                int srow_g = 64*mt + lrow;
                int d = 16*ni + l15;
                Og[((size_t)(b*NS + srow_g))*NE + h*ND + d] = (bf16_t)(oacc[ni][rr] * inv);
            }
        }
    }
}

// ---------------- host launcher ----------------
extern "C" void kernel_launch(void* const* d_in, const int* in_sizes, int n_in,
                              void* d_out, int out_size, void* d_ws, size_t ws_size,
                              hipStream_t stream)
{
    (void)in_sizes; (void)n_in; (void)out_size; (void)ws_size;
    const float* x   = (const float*)d_in[0];
    const float* Wq  = (const float*)d_in[1];
    const float* Wk  = (const float*)d_in[2];
    const float* Wv  = (const float*)d_in[3];
    const float* Wp  = (const float*)d_in[4];
    const float* bp  = (const float*)d_in[5];
    const float* W1  = (const float*)d_in[6];
    const float* b1  = (const float*)d_in[7];
    const float* W2  = (const float*)d_in[8];
    const float* b2  = (const float*)d_in[9];
    const float* g1  = (const float*)d_in[10];
    const float* be1 = (const float*)d_in[11];
    const float* g2  = (const float*)d_in[12];
    const float* be2 = (const float*)d_in[13];
    float* out = (float*)d_out;

    char* ws = (char*)d_ws;
    const size_t SZ = (size_t)NM * NE * 2;           // 48 MiB per bf16 activation
    bf16_t* h_bf  = (bf16_t*)(ws);                   // dead after QKV GEMM
    bf16_t* q_bf  = (bf16_t*)(ws + SZ);              // qkv contiguous: q,k,v
    bf16_t* k_bf  = (bf16_t*)(ws + 2*SZ);
    bf16_t* v_bf  = (bf16_t*)(ws + 3*SZ);
    bf16_t* o_bf  = (bf16_t*)(ws);                   // overlay h (h dead)
    bf16_t* h2_bf = (bf16_t*)(ws);                   // overlay o (o dead after proj)
    bf16_t* hid   = (bf16_t*)(ws + SZ);              // 96 MiB: [32768][1536] over dead q,k
    char* wb = ws + 4*SZ;
    bf16_t* Wcat = (bf16_t*)(wb);                    // [1152][384]
    bf16_t* Wpt  = (bf16_t*)(wb + 884736);           // [384][384]
    bf16_t* W1t  = (bf16_t*)(wb + 884736 + 294912);  // [1536][384]
    bf16_t* W2t  = (bf16_t*)(wb + 884736 + 294912 + 1179648);  // [384][1536]

    wqkv_trans<<<(NH*NE*ND + 255)/256, 256, 0, stream>>>(Wq, Wk, Wv, Wcat);
    wtrans<<<(NE*NE + 255)/256, 256, 0, stream>>>(Wp, Wpt, NE, NE);
    wtrans<<<(NE*4*NE + 255)/256, 256, 0, stream>>>(W1, W1t, NE, 4*NE);
    wtrans<<<(NE*4*NE + 255)/256, 256, 0, stream>>>(W2, W2t, 4*NE, NE);

    ln_kernel<<<NM/4, 256, 0, stream>>>(x, g1, be1, h_bf);

    // QKV: A once in regs, Wcat streamed (18 chunks)
    gemm_areg<1,false><<<NM/128, 512, 0, stream>>>(
        h_bf, NE, Wcat, NE, q_bf, nullptr, nullptr, 1152);

    attn_kernel<<<NB*NH, 256, 0, stream>>>(q_bf, k_bf, v_bf, o_bf);

    // proj: +bias +residual(x), fp32 out (6 chunks)
    gemm_areg<2,false><<<NM/128, 512, 0, stream>>>(
        o_bf, NE, Wpt, NE, out, bp, x, NE);

    ln_kernel<<<NM/4, 256, 0, stream>>>(out, g2, be2, h2_bf);

    // ---- FFN per M-half (hid buffer = 96 MiB) ----
    for (int half = 0; half < 2; half++) {
        const size_t roff = (size_t)half * 32768;
        const bf16_t* h2h = h2_bf + roff * NE;
        float* outh = out + roff * NE;
        // FFN1: hid = relu(h2h @ W1 + b1)  (24 chunks)
        gemm_areg<3,true><<<32768/128, 512, 0, stream>>>(
            h2h, NE, W1t, NE, hid, b1, nullptr, 1536);
        // FFN2: outh += hid @ W2 + b2  (K=1536 streamed, single RMW)
        gemm_ffn2<<<32768/128, 512, 0, stream>>>(hid, W2t, outh, b2);
    }
}